// Round 7
// baseline (158.169 us; speedup 1.0000x reference)
//
#include <hip/hip_runtime.h>

#define K_CLUSTERS 512
#define D_FEAT 64
#define ROWS_PER_WAVE 32
#define ROWS_PER_BLOCK 128   // 4 waves x 32 rows
#define THREADS 256

typedef short bf16x8 __attribute__((ext_vector_type(8)));
typedef short bf16x4 __attribute__((ext_vector_type(4)));
typedef float f32x4 __attribute__((ext_vector_type(4)));

__device__ __forceinline__ unsigned short f32_to_bf16(float f) {
  unsigned int u = __float_as_uint(f);
  u += 0x7fffu + ((u >> 16) & 1u);   // RNE
  return (unsigned short)(u >> 16);
}
__device__ __forceinline__ unsigned short f32_to_bf16_trunc(float f) {
  return (unsigned short)(__float_as_uint(f) >> 16);
}
__device__ __forceinline__ unsigned short f32_to_bf16_rhu(float f) {
  return (unsigned short)((__float_as_uint(f) + 0x8000u) >> 16);
}
__device__ __forceinline__ float bf16_to_f32(unsigned short h) {
  return __uint_as_float(((unsigned int)h) << 16);
}

// ---------------- prep: wave per cluster, lane = feature.
// Emits: chi/clo [K][D] (Phase-A A-operand, hi/lo bf16 split), csqs, and
// PB — centroid-transpose packed in v_mfma_f32_16x16x16_bf16 B-fragment
// order: chunk = T*4 + hpart*2 + rdx (1024 B each). Within a chunk, lane'
// reads 8 u16 at lane'*16B: slot s -> cluster c = T*16 + (lane'>>4)*4 + (s&3),
// feat d = (rdx*2 + (s>>2))*16 + (lane'&15). Main-loop loads are coalesced b128.
__global__ void kmeans_prep(const float* __restrict__ cent,
                            unsigned short* __restrict__ chi,
                            unsigned short* __restrict__ clo,
                            unsigned short* __restrict__ pb,
                            float* __restrict__ csqs) {
  const int wv = threadIdx.x >> 6;
  const int lane = threadIdx.x & 63;
  const int k = blockIdx.x * 4 + wv;    // 128 blocks -> k in [0,512)
  const int f = lane;
  float v = cent[k * D_FEAT + f];
  unsigned short h = f32_to_bf16_trunc(v);
  float rem = v - bf16_to_f32(h);
  unsigned short l = f32_to_bf16(rem);
  chi[k * D_FEAT + f] = h;
  clo[k * D_FEAT + f] = l;
  {
    const int T = k >> 4, win = k & 15;
    const int qw = win >> 2, j = win & 3;
    const int nt = f >> 4, rdx = nt >> 1;
    const int sb = (nt & 1) * 4 + j;
    const int ln = qw * 16 + (f & 15);
    pb[((T * 4 + 0 + rdx) << 9) + ln * 8 + sb] = h;   // hi chunks
    pb[((T * 4 + 2 + rdx) << 9) + ln * 8 + sb] = l;   // lo chunks
  }
  float s = v * v;
#pragma unroll
  for (int d = 1; d < 64; d <<= 1) s += __shfl_xor(s, d, 64);
  if (lane == 0) csqs[k] = s * 14.42695040888963f;    // 10 * log2(e)
}

// ---- per-tile load into slot S (all compile-time slot indices) ----
#define LOADTILE(S, T) do {                                                   \
    const unsigned short* _cb = chi + ((T) * 16 + l16) * 64 + quad * 8;       \
    cgh[S][0] = *(const bf16x8*)(_cb);                                        \
    cgh[S][1] = *(const bf16x8*)(_cb + 32);                                   \
    const unsigned short* _lb = clo + ((T) * 16 + l16) * 64 + quad * 8;       \
    cgl[S][0] = *(const bf16x8*)(_lb);                                        \
    cgl[S][1] = *(const bf16x8*)(_lb + 32);                                   \
    const unsigned short* _pbb = pb + ((T) << 11) + lane * 8;                 \
    pbv[S][0] = *(const bf16x8*)(_pbb);                                       \
    pbv[S][1] = *(const bf16x8*)(_pbb + 512);                                 \
    pbv[S][2] = *(const bf16x8*)(_pbb + 1024);                                \
    pbv[S][3] = *(const bf16x8*)(_pbb + 1536);                                \
    csq4[S] = *(const f32x4*)(csqs + (T) * 16 + quad * 4);                    \
  } while (0)

// ---- swapped QK^T for one row-tile: D[m=cluster(quad*4+r)][n=row(l16)].
// 1.5-trick: (ch+cl)(xh+xl) ~= ch*xh + cl*xh + ch*xl, two parallel chains.
#define ATILE(S, RT, WF, SR) do {                                             \
    f32x4 _ap = {0.f,0.f,0.f,0.f}, _aq = {0.f,0.f,0.f,0.f};                   \
    _ap = __builtin_amdgcn_mfma_f32_16x16x32_bf16(cgh[S][0], xbh[RT][0], _ap, 0,0,0); \
    _aq = __builtin_amdgcn_mfma_f32_16x16x32_bf16(cgh[S][1], xbh[RT][1], _aq, 0,0,0); \
    _ap = __builtin_amdgcn_mfma_f32_16x16x32_bf16(cgl[S][0], xbh[RT][0], _ap, 0,0,0); \
    _aq = __builtin_amdgcn_mfma_f32_16x16x32_bf16(cgl[S][1], xbh[RT][1], _aq, 0,0,0); \
    _ap = __builtin_amdgcn_mfma_f32_16x16x32_bf16(cgh[S][0], xbl[RT][0], _ap, 0,0,0); \
    _aq = __builtin_amdgcn_mfma_f32_16x16x32_bf16(cgh[S][1], xbl[RT][1], _aq, 0,0,0); \
    f32x4 _a = _ap + _aq;                                                     \
    _Pragma("unroll")                                                         \
    for (int _r = 0; _r < 4; ++_r) {                                          \
      float _e = exp2f(fmaf(28.85390081777927f, _a[_r], -csq4[S][_r]));       \
      unsigned short _wq = f32_to_bf16_rhu(_e);                               \
      SR += bf16_to_f32(_wq);                                                 \
      WF[_r] = (short)_wq;                                                    \
    }                                                                         \
  } while (0)

// ---- one K16 PV pair (hi+lo centroid parts) for output n-tile NT.
// GUARD: s_nop before the first MFMA that reads a freshly VALU-written WF
// (CDNA VALU-write -> MFMA-read hazard; asm bypasses compiler hazard insertion).
#define PV1(S, RT, WF, NT, GUARD) do {                                        \
    bf16x8 _ph = pbv[S][(NT) >> 1];                                           \
    bf16x8 _pl = pbv[S][2 + ((NT) >> 1)];                                     \
    bf16x4 _bh = ((NT) & 1) ? __builtin_shufflevector(_ph, _ph, 4,5,6,7)      \
                            : __builtin_shufflevector(_ph, _ph, 0,1,2,3);     \
    bf16x4 _bl = ((NT) & 1) ? __builtin_shufflevector(_pl, _pl, 4,5,6,7)      \
                            : __builtin_shufflevector(_pl, _pl, 0,1,2,3);     \
    asm volatile(GUARD "v_mfma_f32_16x16x16_bf16 %0, %1, %2, %0"              \
                 : "+v"(oacc[RT][NT]) : "v"(WF), "v"(_bh));                   \
    asm volatile("v_mfma_f32_16x16x16_bf16 %0, %1, %2, %0"                    \
                 : "+v"(oacc[RT][NT]) : "v"(WF), "v"(_bl));                   \
  } while (0)

#define PVTILE(S, RT, WF) do {                                                \
    PV1(S, RT, WF, 0, "s_nop 1\n\t");                                         \
    PV1(S, RT, WF, 1, "");                                                    \
    PV1(S, RT, WF, 2, "");                                                    \
    PV1(S, RT, WF, 3, "");                                                    \
  } while (0)

#define COMPUTE(S) do {                                                       \
    bf16x4 _wf0, _wf1;                                                        \
    ATILE(S, 0, _wf0, srow0);                                                 \
    ATILE(S, 1, _wf1, srow1);                                                 \
    PVTILE(S, 0, _wf0);                                                       \
    PVTILE(S, 1, _wf1);                                                       \
  } while (0)

// ---------------- fused main kernel: NO LDS, NO barriers.
// Wave owns 32 rows x all 512 clusters. Swapped QK^T puts weights in the
// exact A-fragment layout of v_mfma_f32_16x16x16_bf16 (m=row on l16,
// k=cluster on quad*4+j), so exp'd weights feed PV directly from registers.
// Row sums: 4 VALU adds/tile/thread + 2 end shuffles (quad reduce).
__global__ __launch_bounds__(THREADS) void kmeans_main(
    const float* __restrict__ x,
    const unsigned short* __restrict__ chi,
    const unsigned short* __restrict__ clo,
    const unsigned short* __restrict__ pb,
    const float* __restrict__ csqs,
    float* __restrict__ out) {
  const int tid  = threadIdx.x;
  const int wv   = tid >> 6;
  const int lane = tid & 63;
  const int l16  = lane & 15;
  const int quad = lane >> 4;
  const long long rowbase = (long long)blockIdx.x * ROWS_PER_BLOCK + wv * ROWS_PER_WAVE;

  // x B-fragments (swapped-QK B-operand): n = row on l16, k = feat quad*8+j
  bf16x8 xbh[2][2], xbl[2][2];
#pragma unroll
  for (int rt = 0; rt < 2; ++rt) {
    const float* xr = x + (rowbase + rt * 16 + l16) * D_FEAT + quad * 8;
#pragma unroll
    for (int ks = 0; ks < 2; ++ks) {
      float4 v0 = *(const float4*)(xr + ks * 32);
      float4 v1 = *(const float4*)(xr + ks * 32 + 4);
      float vv[8] = {v0.x, v0.y, v0.z, v0.w, v1.x, v1.y, v1.z, v1.w};
      bf16x8 hi, lo;
#pragma unroll
      for (int j = 0; j < 8; ++j) {
        unsigned short h = f32_to_bf16_trunc(vv[j]);
        hi[j] = (short)h;
        lo[j] = (short)f32_to_bf16(vv[j] - bf16_to_f32(h));
      }
      xbh[rt][ks] = hi;
      xbl[rt][ks] = lo;
    }
  }

  f32x4 oacc[2][4];
#pragma unroll
  for (int rt = 0; rt < 2; ++rt)
#pragma unroll
    for (int nt = 0; nt < 4; ++nt) oacc[rt][nt] = (f32x4){0.f, 0.f, 0.f, 0.f};
  float srow0 = 0.f, srow1 = 0.f;

  bf16x8 cgh[2][2], cgl[2][2], pbv[2][4];
  f32x4 csq4[2];

  LOADTILE(0, 0);
  LOADTILE(1, 1);
#pragma unroll 2
  for (int T2 = 0; T2 < 16; ++T2) {
    COMPUTE(0);                              // tile 2*T2
    if (T2 < 15) LOADTILE(0, 2 * T2 + 2);
    COMPUTE(1);                              // tile 2*T2+1
    if (T2 < 15) LOADTILE(1, 2 * T2 + 3);
  }

  // MFMA(asm) -> VALU read hazard guard
  asm volatile("s_nop 7\n\ts_nop 7" :::);

  // row sums: reduce over the 4 quads (each quad held a disjoint cluster set)
  srow0 += __shfl_xor(srow0, 16, 64);
  srow0 += __shfl_xor(srow0, 32, 64);
  srow1 += __shfl_xor(srow1, 16, 64);
  srow1 += __shfl_xor(srow1, 32, 64);
  const float inv0 = __builtin_amdgcn_rcpf(srow0);
  const float inv1 = __builtin_amdgcn_rcpf(srow1);

  // epilogue: D[m=row(quad*4+r)][n=feat(l16)] -> normalize + store.
  // inv lives keyed by l16=row; broadcast to (quad,r) via bpermute shuffle.
#pragma unroll
  for (int rt = 0; rt < 2; ++rt) {
    const float invv = rt ? inv1 : inv0;
#pragma unroll
    for (int r = 0; r < 4; ++r) {
      const float ib = __shfl(invv, quad * 4 + r, 64);
      float* ob = out + (rowbase + rt * 16 + quad * 4 + r) * D_FEAT + l16;
#pragma unroll
      for (int nt = 0; nt < 4; ++nt)
        ob[nt * 16] = oacc[rt][nt][r] * ib;
    }
  }
}

extern "C" void kernel_launch(void* const* d_in, const int* in_sizes, int n_in,
                              void* d_out, int out_size, void* d_ws, size_t ws_size,
                              hipStream_t stream) {
  const float* x    = (const float*)d_in[0];
  const float* cent = (const float*)d_in[1];
  float* out        = (float*)d_out;

  unsigned short* chi = (unsigned short*)d_ws;            // [512][64]
  unsigned short* clo = chi + K_CLUSTERS * D_FEAT;        // [512][64]
  unsigned short* pb  = clo + K_CLUSTERS * D_FEAT;        // 65536 u16 packed PV-B
  float*          csqs = (float*)(pb + 65536);            // [512]

  kmeans_prep<<<K_CLUSTERS / 4, 256, 0, stream>>>(cent, chi, clo, pb, csqs);

  int nrows = in_sizes[0] / D_FEAT;  // 131072
  kmeans_main<<<nrows / ROWS_PER_BLOCK, THREADS, 0, stream>>>(
      x, chi, clo, pb, csqs, out);
}

// Round 8
// 151.473 us; speedup vs baseline: 1.0442x; 1.0442x over previous
//
#include <hip/hip_runtime.h>

#define K_CLUSTERS 512
#define D_FEAT 64
#define ROWS_PER_WAVE 32
#define ROWS_PER_BLOCK 128   // 4 waves x 32 rows
#define THREADS 256

typedef short bf16x8 __attribute__((ext_vector_type(8)));
typedef short bf16x4 __attribute__((ext_vector_type(4)));
typedef float f32x4 __attribute__((ext_vector_type(4)));

__device__ __forceinline__ unsigned short f32_to_bf16(float f) {
  unsigned int u = __float_as_uint(f);
  u += 0x7fffu + ((u >> 16) & 1u);   // RNE
  return (unsigned short)(u >> 16);
}
__device__ __forceinline__ unsigned short f32_to_bf16_trunc(float f) {
  return (unsigned short)(__float_as_uint(f) >> 16);
}
__device__ __forceinline__ unsigned short f32_to_bf16_rhu(float f) {
  return (unsigned short)((__float_as_uint(f) + 0x8000u) >> 16);
}
__device__ __forceinline__ float bf16_to_f32(unsigned short h) {
  return __uint_as_float(((unsigned int)h) << 16);
}

// ---------------- prep: wave per cluster, lane = feature.
// Emits one combined buffer cpk (u16, 256KB) laid out per 32-cluster PAIR
// (8192 u16 = 16KB each):
//   [qa tile 2P : 2048 u16][qa tile 2P+1 : 2048][pb pair P : 4096]
// qa (QK A-frag, 16x16x32, A[m=cluster][k=feat]): part(0=hi ks0,1=hi ks1,
//   2=lo ks0,3=lo ks1) x lane L=(quad*16+m) x j:  feat = ks*32+quad*8+j.
// pb (PV B-frag, 16x16x32, B[k=cluster][n=feat]): part(hipart*4+nt) x lane
//   L'=(q'*16+n16) x j', cluster bijection: cin<16 -> (q'=cin>>2, j'=cin&3),
//   cin>=16 -> (q'=(cin&15)>>2, j'=4+(cin&3))  == A-side WF concat order.
// csqs[k] = 10*log2e*|c|^2 (separate, after cpk).
__global__ void kmeans_prep(const float* __restrict__ cent,
                            unsigned short* __restrict__ cpk,
                            float* __restrict__ csqs) {
  const int wv = threadIdx.x >> 6;
  const int lane = threadIdx.x & 63;
  const int k = blockIdx.x * 4 + wv;    // 128 blocks -> k in [0,512)
  const int f = lane;
  float v = cent[k * D_FEAT + f];
  unsigned short h = f32_to_bf16_trunc(v);
  float rem = v - bf16_to_f32(h);
  unsigned short l = f32_to_bf16(rem);
  // qa
  {
    const int T = k >> 4, m = k & 15;
    const int ks = f >> 5, quad = (f >> 3) & 3, j = f & 7;
    const int L = quad * 16 + m;
    const unsigned base = (unsigned)(T >> 1) * 8192u + (unsigned)(T & 1) * 2048u;
    cpk[base + ks * 512 + L * 8 + j] = h;
    cpk[base + (2 + ks) * 512 + L * 8 + j] = l;
  }
  // pb
  {
    const int P = k >> 5, cin = k & 31;
    const int qp = (cin & 15) >> 2;
    const int jp = ((cin >> 4) << 2) | (cin & 3);
    const int nt = f >> 4, n16 = f & 15;
    const int Lp = qp * 16 + n16;
    const unsigned base = (unsigned)P * 8192u + 4096u;
    cpk[base + nt * 512 + Lp * 8 + jp] = h;
    cpk[base + (4 + nt) * 512 + Lp * 8 + jp] = l;
  }
  float s = v * v;
#pragma unroll
  for (int d = 1; d < 64; d <<= 1) s += __shfl_xor(s, d, 64);
  if (lane == 0) csqs[k] = s * 14.42695040888963f;    // 10 * log2(e)
}

// ---------------- fused main kernel, LDS-shared centroids.
// Wave owns 32 rows x all 512 clusters (swapped QK^T keeps weights in the
// exact K32 A-frag layout; no W round-trip). The 4 waves SHARE each staged
// 16KB pair of packed operands (R7 lesson: private per-wave streams = 4x L2
// traffic = the regression). Double-buffered, 1 barrier/pair, reg-staged
// copy with early-issued loads (T14). All MFMAs are builtins (R7's volatile
// asm serialized the stream); PV at K32 (full rate).
__global__ __launch_bounds__(THREADS) void kmeans_main(
    const float* __restrict__ x,
    const unsigned short* __restrict__ cpk,
    const float* __restrict__ csqs,
    float* __restrict__ out) {
  __shared__ __attribute__((aligned(16))) unsigned short lds[16384];  // 32KB, 2 x 16KB

  const int tid  = threadIdx.x;
  const int wv   = tid >> 6;
  const int lane = tid & 63;
  const int l16  = lane & 15;
  const int quad = lane >> 4;
  const long long rowbase = (long long)blockIdx.x * ROWS_PER_BLOCK + wv * ROWS_PER_WAVE;

  // x B-fragments (swapped-QK B-operand): n = row on l16, k = feat quad*8+j
  bf16x8 xbh[2][2], xbl[2][2];
#pragma unroll
  for (int rt = 0; rt < 2; ++rt) {
    const float* xr = x + (rowbase + rt * 16 + l16) * D_FEAT + quad * 8;
#pragma unroll
    for (int ks = 0; ks < 2; ++ks) {
      float4 v0 = *(const float4*)(xr + ks * 32);
      float4 v1 = *(const float4*)(xr + ks * 32 + 4);
      float vv[8] = {v0.x, v0.y, v0.z, v0.w, v1.x, v1.y, v1.z, v1.w};
      bf16x8 hi, lo;
#pragma unroll
      for (int j = 0; j < 8; ++j) {
        unsigned short h = f32_to_bf16_trunc(vv[j]);
        hi[j] = (short)h;
        lo[j] = (short)f32_to_bf16(vv[j] - bf16_to_f32(h));
      }
      xbh[rt][ks] = hi;
      xbl[rt][ks] = lo;
    }
  }

  f32x4 oacc[2][4];
#pragma unroll
  for (int rt = 0; rt < 2; ++rt)
#pragma unroll
    for (int nt = 0; nt < 4; ++nt) oacc[rt][nt] = (f32x4){0.f, 0.f, 0.f, 0.f};
  float srow0 = 0.f, srow1 = 0.f;

  // ---- prologue: stage pairs 0 and 1 (reg-staged, lane-linear => no conflicts)
  {
    bf16x8 ga[4], gb[4];
#pragma unroll
    for (int i = 0; i < 4; ++i) ga[i] = *(const bf16x8*)(cpk + (i * 256 + tid) * 8);
#pragma unroll
    for (int i = 0; i < 4; ++i) gb[i] = *(const bf16x8*)(cpk + 8192 + (i * 256 + tid) * 8);
#pragma unroll
    for (int i = 0; i < 4; ++i) *(bf16x8*)(lds + (i * 256 + tid) * 8) = ga[i];
#pragma unroll
    for (int i = 0; i < 4; ++i) *(bf16x8*)(lds + 8192 + (i * 256 + tid) * 8) = gb[i];
  }
  __syncthreads();

#pragma unroll
  for (int P = 0; P < 16; ++P) {
    const int b = P & 1;
    const bool pf = (P + 2) < 16;
    // early-issue next-pair loads; HBM/L2 latency hides under this pair's MFMAs
    bf16x8 g[4];
    if (pf) {
#pragma unroll
      for (int i = 0; i < 4; ++i)
        g[i] = *(const bf16x8*)(cpk + (P + 2) * 8192 + (i * 256 + tid) * 8);
    }
    const unsigned short* lb = lds + b * 8192;
    // QK A-frags for tiles 2P (E) and 2P+1 (O)
    bf16x8 qh[2][2], ql[2][2];
#pragma unroll
    for (int tl = 0; tl < 2; ++tl)
#pragma unroll
      for (int ks = 0; ks < 2; ++ks) {
        qh[tl][ks] = *(const bf16x8*)(lb + tl * 2048 + ks * 512 + lane * 8);
        ql[tl][ks] = *(const bf16x8*)(lb + tl * 2048 + (2 + ks) * 512 + lane * 8);
      }
    // PV B-frags (K32 cluster-pair order)
    bf16x8 pvh[4], pvl[4];
#pragma unroll
    for (int nt = 0; nt < 4; ++nt) {
      pvh[nt] = *(const bf16x8*)(lb + 4096 + nt * 512 + lane * 8);
      pvl[nt] = *(const bf16x8*)(lb + 4096 + (4 + nt) * 512 + lane * 8);
    }
    const f32x4 csqE = *(const f32x4*)(csqs + P * 32 + quad * 4);
    const f32x4 csqO = *(const f32x4*)(csqs + P * 32 + 16 + quad * 4);

    bf16x8 wfc[2];
#pragma unroll
    for (int rt = 0; rt < 2; ++rt) {
      // tile E: 1.5-trick, two parallel chains
      f32x4 ap = {0.f,0.f,0.f,0.f}, aq = {0.f,0.f,0.f,0.f};
      ap = __builtin_amdgcn_mfma_f32_16x16x32_bf16(qh[0][0], xbh[rt][0], ap, 0,0,0);
      aq = __builtin_amdgcn_mfma_f32_16x16x32_bf16(qh[0][1], xbh[rt][1], aq, 0,0,0);
      ap = __builtin_amdgcn_mfma_f32_16x16x32_bf16(ql[0][0], xbh[rt][0], ap, 0,0,0);
      aq = __builtin_amdgcn_mfma_f32_16x16x32_bf16(ql[0][1], xbh[rt][1], aq, 0,0,0);
      ap = __builtin_amdgcn_mfma_f32_16x16x32_bf16(qh[0][0], xbl[rt][0], ap, 0,0,0);
      aq = __builtin_amdgcn_mfma_f32_16x16x32_bf16(qh[0][1], xbl[rt][1], aq, 0,0,0);
      f32x4 aE = ap + aq;
      // tile O
      f32x4 bp = {0.f,0.f,0.f,0.f}, bq = {0.f,0.f,0.f,0.f};
      bp = __builtin_amdgcn_mfma_f32_16x16x32_bf16(qh[1][0], xbh[rt][0], bp, 0,0,0);
      bq = __builtin_amdgcn_mfma_f32_16x16x32_bf16(qh[1][1], xbh[rt][1], bq, 0,0,0);
      bp = __builtin_amdgcn_mfma_f32_16x16x32_bf16(ql[1][0], xbh[rt][0], bp, 0,0,0);
      bq = __builtin_amdgcn_mfma_f32_16x16x32_bf16(ql[1][1], xbh[rt][1], bq, 0,0,0);
      bp = __builtin_amdgcn_mfma_f32_16x16x32_bf16(qh[1][0], xbl[rt][0], bp, 0,0,0);
      bq = __builtin_amdgcn_mfma_f32_16x16x32_bf16(qh[1][1], xbl[rt][1], bq, 0,0,0);
      f32x4 aO = bp + bq;
      // exp + pack into K32 A-frag halves (j<4 = tile E, j>=4 = tile O)
      float sr = 0.f;
#pragma unroll
      for (int r = 0; r < 4; ++r) {
        float eE = exp2f(fmaf(28.85390081777927f, aE[r], -csqE[r]));
        unsigned short wE = f32_to_bf16_rhu(eE);
        sr += bf16_to_f32(wE);
        wfc[rt][r] = (short)wE;
        float eO = exp2f(fmaf(28.85390081777927f, aO[r], -csqO[r]));
        unsigned short wO = f32_to_bf16_rhu(eO);
        sr += bf16_to_f32(wO);
        wfc[rt][4 + r] = (short)wO;
      }
      if (rt) srow1 += sr; else srow0 += sr;
    }
    // PV: K32, hi + lo centroid parts
#pragma unroll
    for (int rt = 0; rt < 2; ++rt)
#pragma unroll
      for (int nt = 0; nt < 4; ++nt) {
        oacc[rt][nt] = __builtin_amdgcn_mfma_f32_16x16x32_bf16(wfc[rt], pvh[nt], oacc[rt][nt], 0,0,0);
        oacc[rt][nt] = __builtin_amdgcn_mfma_f32_16x16x32_bf16(wfc[rt], pvl[nt], oacc[rt][nt], 0,0,0);
      }
    __syncthreads();   // all waves done reading buf b
    if (pf) {
#pragma unroll
      for (int i = 0; i < 4; ++i)
        *(bf16x8*)(lds + b * 8192 + (i * 256 + tid) * 8) = g[i];
    }
    // writes land before next iteration's barrier; buf b is next read at P+2
  }

  // row sums: reduce over the 4 quads (disjoint cluster subsets per quad)
  srow0 += __shfl_xor(srow0, 16, 64);
  srow0 += __shfl_xor(srow0, 32, 64);
  srow1 += __shfl_xor(srow1, 16, 64);
  srow1 += __shfl_xor(srow1, 32, 64);
  const float inv0 = __builtin_amdgcn_rcpf(srow0);
  const float inv1 = __builtin_amdgcn_rcpf(srow1);

  // epilogue: D[m=row(quad*4+r)][n=feat(l16+nt*16)] -> normalize + store
#pragma unroll
  for (int rt = 0; rt < 2; ++rt) {
    const float invv = rt ? inv1 : inv0;
#pragma unroll
    for (int r = 0; r < 4; ++r) {
      const float ib = __shfl(invv, quad * 4 + r, 64);
      float* ob = out + (rowbase + rt * 16 + quad * 4 + r) * D_FEAT + l16;
#pragma unroll
      for (int nt = 0; nt < 4; ++nt)
        ob[nt * 16] = oacc[rt][nt][r] * ib;
    }
  }
}

extern "C" void kernel_launch(void* const* d_in, const int* in_sizes, int n_in,
                              void* d_out, int out_size, void* d_ws, size_t ws_size,
                              hipStream_t stream) {
  const float* x    = (const float*)d_in[0];
  const float* cent = (const float*)d_in[1];
  float* out        = (float*)d_out;

  unsigned short* cpk  = (unsigned short*)d_ws;       // 131072 u16 = 256KB packed
  float*          csqs = (float*)(cpk + 131072);      // [512]

  kmeans_prep<<<K_CLUSTERS / 4, 256, 0, stream>>>(cent, cpk, csqs);

  int nrows = in_sizes[0] / D_FEAT;  // 131072
  kmeans_main<<<nrows / ROWS_PER_BLOCK, THREADS, 0, stream>>>(
      x, cpk, csqs, out);
}